// Round 20
// baseline (878.555 us; speedup 1.0000x reference)
//
#include <hip/hip_runtime.h>

#define Bb 64
#define Tt 2048
#define Ii 64
#define Hh 128
#define Gg 384   // 3*H
#define Oo 64

#define LOG2E 1.44269504088896340736f

typedef _Float16 f16;
typedef _Float16 half8 __attribute__((ext_vector_type(8)));
typedef __fp16 fp16v2 __attribute__((ext_vector_type(2)));   // cvt_pkrtz native type
typedef float f32x4 __attribute__((ext_vector_type(4)));
typedef unsigned int u32;
typedef unsigned int u32x4 __attribute__((ext_vector_type(4)));

static __device__ __forceinline__ float cvt_lo(u32 u) {
    fp16v2 v = __builtin_bit_cast(fp16v2, u);
    return (float)v[0];
}
static __device__ __forceinline__ float cvt_hi(u32 u) {
    fp16v2 v = __builtin_bit_cast(fp16v2, u);
    return (float)v[1];
}

// ---------------- K1: MFMA x-projection (R16-validated structure).
// R19: outputs PRE-SCALED for exp2 gates — r/z rows x log2e, n rows x 2log2e
// (weights and biases scaled at fragment load; staging is internal-only).
__global__ __launch_bounds__(256, 2) void xproj_mfma(
    const float* __restrict__ inputs, const float* __restrict__ W_ih,
    const float* __restrict__ b_ih, f16* __restrict__ xR, f16* __restrict__ xZN)
{
    __shared__ __align__(16) unsigned char xls[64 * 128];  // [row][2k B] f16, swz

    const int tid = threadIdx.x;
    const int w   = tid >> 6;
    const int l   = tid & 63;
    const int lo  = l & 15;
    const int hi  = l >> 4;
    const int rowBase = blockIdx.x * 64;

    // B fragments + biases: wave w covers gate-cols [w*96, w*96+96).
    half8 Bfr[6][2];
    float bias[6];
#pragma unroll
    for (int nt = 0; nt < 6; ++nt) {
        const int g = w * 96 + nt * 16 + lo;
        const float sc = (g >= 256) ? (2.f * LOG2E) : LOG2E;
#pragma unroll
        for (int ks = 0; ks < 2; ++ks) {
            const float* wp = W_ih + (size_t)g * 64 + ks * 32 + hi * 8;
            half8 hv;
#pragma unroll
            for (int q = 0; q < 8; ++q) hv[q] = (f16)(wp[q] * sc);
            Bfr[nt][ks] = hv;
        }
        bias[nt] = b_ih[g] * sc;
    }

    // Stage x-tile: thread covers (row r = tid>>2, k c0 = (tid&3)*16), 16 f32.
    {
        const int r  = tid >> 2;
        const int c0 = (tid & 3) * 16;
        const float4* src = (const float4*)(inputs + (size_t)(rowBase + r) * 64 + c0);
        const float4 v0 = src[0], v1 = src[1], v2 = src[2], v3 = src[3];
        u32x4 d0, d1;
        d0[0] = __builtin_bit_cast(u32, __builtin_amdgcn_cvt_pkrtz(v0.x, v0.y));
        d0[1] = __builtin_bit_cast(u32, __builtin_amdgcn_cvt_pkrtz(v0.z, v0.w));
        d0[2] = __builtin_bit_cast(u32, __builtin_amdgcn_cvt_pkrtz(v1.x, v1.y));
        d0[3] = __builtin_bit_cast(u32, __builtin_amdgcn_cvt_pkrtz(v1.z, v1.w));
        d1[0] = __builtin_bit_cast(u32, __builtin_amdgcn_cvt_pkrtz(v2.x, v2.y));
        d1[1] = __builtin_bit_cast(u32, __builtin_amdgcn_cvt_pkrtz(v2.z, v2.w));
        d1[2] = __builtin_bit_cast(u32, __builtin_amdgcn_cvt_pkrtz(v3.x, v3.y));
        d1[3] = __builtin_bit_cast(u32, __builtin_amdgcn_cvt_pkrtz(v3.z, v3.w));
        const int base = r * 128;
        const int sw   = (r & 7) << 4;
        *(u32x4*)(&xls[base + ((2 * c0) ^ sw)])      = d0;
        *(u32x4*)(&xls[base + ((2 * c0 + 16) ^ sw)]) = d1;
    }
    __syncthreads();

    // A fragments: tile m rows [m*16, m*16+16), lane row = m*16+lo, k-chunk hi*8.
    half8 Af[4][2];
#pragma unroll
    for (int m = 0; m < 4; ++m)
#pragma unroll
        for (int ks = 0; ks < 2; ++ks) {
            const int row = m * 16 + lo;
            Af[m][ks] = *(const half8*)(
                &xls[row * 128 + ((ks * 64 + hi * 16) ^ ((row & 7) << 4))]);
        }

    // Compute + store. C/D: col = lo, row = hi*4 + q.
#pragma unroll
    for (int nt = 0; nt < 6; ++nt) {
        const int g    = w * 96 + nt * 16 + lo;
        const int gate = g >> 7;
        const int j    = g & 127;
#pragma unroll
        for (int m = 0; m < 4; ++m) {
            f32x4 acc = {bias[nt], bias[nt], bias[nt], bias[nt]};
            acc = __builtin_amdgcn_mfma_f32_16x16x32_f16(Af[m][0], Bfr[nt][0], acc, 0, 0, 0);
            acc = __builtin_amdgcn_mfma_f32_16x16x32_f16(Af[m][1], Bfr[nt][1], acc, 0, 0, 0);
            const int r0 = rowBase + m * 16 + hi * 4;
#pragma unroll
            for (int q = 0; q < 4; ++q) {
                const f16 val = (f16)acc[q];
                const size_t row = (size_t)(r0 + q);
                if (gate == 0)      xR[row * 128 + j] = val;
                else if (gate == 1) xZN[row * 256 + 2 * j] = val;
                else                xZN[row * 256 + 2 * j + 1] = val;
            }
        }
    }
}

// ---------------- K2: MFMA recurrence + fused out-proj (R18-validated).
// R19: (1) W_hh/b_hh rows pre-scaled (r/z x log2e, n x 2log2e) -> gate eval is
// pure exp2 via __builtin_amdgcn_exp2f (v_exp_f32 is base-2 native):
// r = rcp(1+exp2(-pr)); n = 1-2*rcp(exp2(a')+1).
// (2) s_setprio(1) around the gate-MFMA cluster (T5).
__global__ __launch_bounds__(512, 2) void gru_mfma(
    const float* __restrict__ W_hh, const float* __restrict__ b_hh,
    const f16* __restrict__ xR, const f16* __restrict__ xZN,
    const float* __restrict__ W_out, const float* __restrict__ b_out,
    float* __restrict__ latents, float* __restrict__ out)
{
    __shared__ __align__(16) unsigned char hsm[2][1024];  // [b][j] f16, b-parity XOR

    const int tid = threadIdx.x;
    const int w   = tid >> 6;
    const int l   = tid & 63;
    const int lo  = l & 15;
    const int hi  = l >> 4;
    const int jj  = w * 16 + lo;      // this lane's hidden column
    const int bb0 = blockIdx.x * 4;   // 4 batches per block

    // Gate B fragments: lane lo -> col jj, hi -> k-chunk of 8. Pre-scaled.
    half8 Bf[3][4];
#pragma unroll
    for (int gt = 0; gt < 3; ++gt) {
        const float sc = (gt == 2) ? (2.f * LOG2E) : LOG2E;
#pragma unroll
        for (int ks = 0; ks < 4; ++ks) {
            const float* wp = W_hh + (size_t)(gt * 128 + jj) * 128 + ks * 32 + hi * 8;
            half8 hv;
#pragma unroll
            for (int q = 0; q < 8; ++q) hv[q] = (f16)(wp[q] * sc);
            Bf[gt][ks] = hv;
        }
    }
#pragma unroll
    for (int gt = 0; gt < 3; ++gt)
#pragma unroll
        for (int ks = 0; ks < 4; ++ks)
            asm volatile("" : "+v"(Bf[gt][ks]));

    // Out-proj B fragments: all waves hold W_out rows (jj & 63). Unscaled.
    const int oc = jj & 63;
    half8 Bw[4];
#pragma unroll
    for (int ks = 0; ks < 4; ++ks) {
        const float* wp = W_out + (size_t)oc * 128 + ks * 32 + hi * 8;
        half8 hv;
#pragma unroll
        for (int q = 0; q < 8; ++q) hv[q] = (f16)wp[q];
        Bw[ks] = hv;
    }
#pragma unroll
    for (int ks = 0; ks < 4; ++ks) asm volatile("" : "+v"(Bw[ks]));
    const float bo = b_out[oc];

    const float br = b_hh[jj]       * LOG2E;
    const float bz = b_hh[128 + jj] * LOG2E;
    const float bn = b_hh[256 + jj] * (2.f * LOG2E);

    // Strength-reduced per-lane streams for (b = bb0 + hi, j = jj).
    const f16* xrpA  = xR  + (size_t)(bb0 + hi) * Tt * 128 + jj;          // t even
    const f16* xrpB  = xrpA + 128;                                        // t odd
    const f16* xznpA = xZN + (size_t)(bb0 + hi) * Tt * 256 + 2 * jj;
    const f16* xznpB = xznpA + 256;
    float*     latp  = latents + (size_t)(bb0 + hi) * Tt * 128 + jj;
    float*     outp  = out     + (size_t)(bb0 + hi) * Tt * 64  + oc;

    // LDS addresses (R9-validated layout; direct per-lane b16 write).
    const int waddr = hi * 256 + ((2 * jj) ^ ((hi & 1) << 6));
    const int rxor  = ((lo >> 2) & 1) << 6;
    const int rb    = (lo << 6);   // = (lo>>2)*256 for lo in {0,4,8,12}

    // 2-deep x prefetch: set A serves even t, set B serves odd t.
    f16 xrA = xrpA[0];
    f16 xrB = xrpB[0];
    u32 xzA = *(const u32*)xznpA;
    u32 xzB = *(const u32*)xznpB;
    xrpA += 256; xrpB += 256;       // advance 2 steps: 2 x 128 f16
    xznpA += 512; xznpB += 512;     // advance 2 steps: 2 x 256 f16

    float hreg = 0.f;
    half8 A[4];
    {
        half8 z8 = {};
#pragma unroll
        for (int ks = 0; ks < 4; ++ks) A[ks] = z8;   // rows != 4b stay zero forever
    }

// Out-proj for row TR (A[ks] = latents[TR] fragments); COND picks wave group.
#define OUTSTEP(TR, COND)                                                        \
    if (COND) {                                                                  \
        f32x4 aco0 = {bo, bo, bo, bo};                                           \
        f32x4 aco1 = {0.f, 0.f, 0.f, 0.f};                                       \
        aco0 = __builtin_amdgcn_mfma_f32_16x16x32_f16(A[0], Bw[0], aco0, 0, 0, 0); \
        aco1 = __builtin_amdgcn_mfma_f32_16x16x32_f16(A[1], Bw[1], aco1, 0, 0, 0); \
        aco0 = __builtin_amdgcn_mfma_f32_16x16x32_f16(A[2], Bw[2], aco0, 0, 0, 0); \
        aco1 = __builtin_amdgcn_mfma_f32_16x16x32_f16(A[3], Bw[3], aco1, 0, 0, 0); \
        outp[(size_t)(TR) * 64] = aco0[0] + aco1[0];                             \
    }

#define GSTEP(T, WP, XRC, XZC, XRP, XZNP, OCOND)                                 \
    {                                                                            \
        const int t_ = (T);                                                      \
        const float xr_ = (float)XRC;                                            \
        const float xz_ = cvt_lo(XZC);                                           \
        const float xn_ = cvt_hi(XZC);                                           \
        if (t_ + 2 < Tt) {                                                       \
            XRC = XRP[0];                                                        \
            XZC = *(const u32*)XZNP;                                             \
            XRP += 256; XZNP += 512;                                             \
        }                                                                        \
        /* gate MFMAs: 2+2 split chains per gate; prio-boosted (T5) */           \
        f32x4 accr0 = {br, br, br, br},     accr1 = {0.f, 0.f, 0.f, 0.f};        \
        f32x4 accz0 = {bz, bz, bz, bz},     accz1 = {0.f, 0.f, 0.f, 0.f};        \
        f32x4 accn0 = {bn, bn, bn, bn},     accn1 = {0.f, 0.f, 0.f, 0.f};        \
        __builtin_amdgcn_s_setprio(1);                                           \
        accr0 = __builtin_amdgcn_mfma_f32_16x16x32_f16(A[0], Bf[0][0], accr0, 0, 0, 0); \
        accz0 = __builtin_amdgcn_mfma_f32_16x16x32_f16(A[0], Bf[1][0], accz0, 0, 0, 0); \
        accn0 = __builtin_amdgcn_mfma_f32_16x16x32_f16(A[0], Bf[2][0], accn0, 0, 0, 0); \
        accr1 = __builtin_amdgcn_mfma_f32_16x16x32_f16(A[1], Bf[0][1], accr1, 0, 0, 0); \
        accz1 = __builtin_amdgcn_mfma_f32_16x16x32_f16(A[1], Bf[1][1], accz1, 0, 0, 0); \
        accn1 = __builtin_amdgcn_mfma_f32_16x16x32_f16(A[1], Bf[2][1], accn1, 0, 0, 0); \
        accr0 = __builtin_amdgcn_mfma_f32_16x16x32_f16(A[2], Bf[0][2], accr0, 0, 0, 0); \
        accz0 = __builtin_amdgcn_mfma_f32_16x16x32_f16(A[2], Bf[1][2], accz0, 0, 0, 0); \
        accn0 = __builtin_amdgcn_mfma_f32_16x16x32_f16(A[2], Bf[2][2], accn0, 0, 0, 0); \
        accr1 = __builtin_amdgcn_mfma_f32_16x16x32_f16(A[3], Bf[0][3], accr1, 0, 0, 0); \
        accz1 = __builtin_amdgcn_mfma_f32_16x16x32_f16(A[3], Bf[1][3], accz1, 0, 0, 0); \
        accn1 = __builtin_amdgcn_mfma_f32_16x16x32_f16(A[3], Bf[2][3], accn1, 0, 0, 0); \
        __builtin_amdgcn_s_setprio(0);                                           \
        /* off-chain while gate chains drain: out-proj of row t-1 */             \
        if (t_ > 0) { OUTSTEP(t_ - 1, OCOND) }                                   \
        /* batch bb0+hi row (=4*hi) lives in reg 0; exp2-native gates */         \
        const float r = __builtin_amdgcn_rcpf(                                   \
            1.f + __builtin_amdgcn_exp2f(-(accr0[0] + accr1[0] + xr_)));         \
        const float z = __builtin_amdgcn_rcpf(                                   \
            1.f + __builtin_amdgcn_exp2f(-(accz0[0] + accz1[0] + xz_)));         \
        const float ap = xn_ + r * (accn0[0] + accn1[0]);                        \
        const float n = 1.f - 2.f * __builtin_amdgcn_rcpf(                       \
            __builtin_amdgcn_exp2f(ap) + 1.f);                                   \
        const float hnew = n + z * (hreg - n);                                   \
        hreg = hnew;                                                             \
        latp[(size_t)t_ * 128] = hnew;                                           \
        *(f16*)(&hsm[WP][waddr]) = (f16)hnew;   /* direct b16, layout-identical */ \
        __syncthreads();                                                         \
        if (!(lo & 3)) {                                                         \
            _Pragma("unroll") for (int ks = 0; ks < 4; ++ks)                     \
                A[ks] = *(const half8*)(&hsm[WP][rb + ((ks * 64 + hi * 16) ^ rxor)]); \
        }                                                                        \
    }

    for (int t = 0; t < Tt; t += 2) {
        GSTEP(t,     0, xrA, xzA, xrpA, xznpA, (w >= 4))  // row t-1 odd -> waves 4-7
        GSTEP(t + 1, 1, xrB, xzB, xrpB, xznpB, (w < 4))   // row t even -> waves 0-3
    }

    // Epilogue: row Tt-1 (odd) out-proj from the final A fragments.
    OUTSTEP(Tt - 1, (w >= 4))
#undef GSTEP
#undef OUTSTEP
}

extern "C" void kernel_launch(void* const* d_in, const int* in_sizes, int n_in,
                              void* d_out, int out_size, void* d_ws, size_t ws_size,
                              hipStream_t stream) {
    const float* inputs = (const float*)d_in[0];
    const float* W_ih   = (const float*)d_in[1];
    const float* W_hh   = (const float*)d_in[2];
    const float* b_ih   = (const float*)d_in[3];
    const float* b_hh   = (const float*)d_in[4];
    const float* W_out  = (const float*)d_in[5];
    const float* b_out  = (const float*)d_in[6];

    float* out     = (float*)d_out;
    float* latents = out + (size_t)Bb * Tt * Oo;

    // x_proj staging (f16): r-gates [B][T][128]; z/n interleaved [B][T][128][2].
    const size_t xbytes = (size_t)Bb * Tt * Gg * sizeof(f16);  // 100,663,296 B
    f16 *xR, *xZN;
    if (ws_size >= xbytes) {
        xR  = (f16*)d_ws;
        xZN = xR + (size_t)Bb * Tt * Hh;
    } else {
        // Alias into d_out: xR fits exactly in the output region, xZN exactly
        // in the latents region (rows byte-aligned 1:1). K2's latents store at
        // (b,t) hits xZN row (b,t), last read at step t-2's prefetch; K2's out
        // store at (b,t-1) hits xR row (b,t-1), last read at step t-3. Both
        // strictly read-before-write per lane-column.
        xR  = (f16*)d_out;
        xZN = (f16*)latents;
    }

    xproj_mfma<<<2048, 256, 0, stream>>>(inputs, W_ih, b_ih, xR, xZN);
    gru_mfma<<<16, 512, 0, stream>>>(W_hh, b_hh, xR, xZN, W_out, b_out,
                                     latents, out);
}

// Round 21
// 864.674 us; speedup vs baseline: 1.0161x; 1.0161x over previous
//
#include <hip/hip_runtime.h>

#define Bb 64
#define Tt 2048
#define Ii 64
#define Hh 128
#define Gg 384   // 3*H
#define Oo 64

typedef _Float16 f16;
typedef _Float16 half8 __attribute__((ext_vector_type(8)));
typedef __fp16 fp16v2 __attribute__((ext_vector_type(2)));   // cvt_pkrtz native type
typedef float f32x4 __attribute__((ext_vector_type(4)));
typedef unsigned int u32;
typedef unsigned int u32x4 __attribute__((ext_vector_type(4)));

static __device__ __forceinline__ float cvt_lo(u32 u) {
    fp16v2 v = __builtin_bit_cast(fp16v2, u);
    return (float)v[0];
}
static __device__ __forceinline__ float cvt_hi(u32 u) {
    fp16v2 v = __builtin_bit_cast(fp16v2, u);
    return (float)v[1];
}

// ---------------- K1: MFMA x-projection. 2048 blocks x 256 threads, 64 rows each.
// (R16-validated.) xg[row,g] = x[row,:]@W_ih[g,:] + b_ih[g], f16 out:
// g<128 -> xR[row][g]; [128,256) -> xZN[row][2(g-128)]; [256,384) -> xZN[..+1].
__global__ __launch_bounds__(256, 2) void xproj_mfma(
    const float* __restrict__ inputs, const float* __restrict__ W_ih,
    const float* __restrict__ b_ih, f16* __restrict__ xR, f16* __restrict__ xZN)
{
    __shared__ __align__(16) unsigned char xls[64 * 128];  // [row][2k B] f16, swz

    const int tid = threadIdx.x;
    const int w   = tid >> 6;
    const int l   = tid & 63;
    const int lo  = l & 15;
    const int hi  = l >> 4;
    const int rowBase = blockIdx.x * 64;

    // B fragments + biases: wave w covers gate-cols [w*96, w*96+96).
    half8 Bfr[6][2];
    float bias[6];
#pragma unroll
    for (int nt = 0; nt < 6; ++nt) {
        const int g = w * 96 + nt * 16 + lo;
#pragma unroll
        for (int ks = 0; ks < 2; ++ks) {
            const float* wp = W_ih + (size_t)g * 64 + ks * 32 + hi * 8;
            half8 hv;
#pragma unroll
            for (int q = 0; q < 8; ++q) hv[q] = (f16)wp[q];
            Bfr[nt][ks] = hv;
        }
        bias[nt] = b_ih[g];
    }

    // Stage x-tile: thread covers (row r = tid>>2, k c0 = (tid&3)*16), 16 f32.
    {
        const int r  = tid >> 2;
        const int c0 = (tid & 3) * 16;
        const float4* src = (const float4*)(inputs + (size_t)(rowBase + r) * 64 + c0);
        const float4 v0 = src[0], v1 = src[1], v2 = src[2], v3 = src[3];
        u32x4 d0, d1;
        d0[0] = __builtin_bit_cast(u32, __builtin_amdgcn_cvt_pkrtz(v0.x, v0.y));
        d0[1] = __builtin_bit_cast(u32, __builtin_amdgcn_cvt_pkrtz(v0.z, v0.w));
        d0[2] = __builtin_bit_cast(u32, __builtin_amdgcn_cvt_pkrtz(v1.x, v1.y));
        d0[3] = __builtin_bit_cast(u32, __builtin_amdgcn_cvt_pkrtz(v1.z, v1.w));
        d1[0] = __builtin_bit_cast(u32, __builtin_amdgcn_cvt_pkrtz(v2.x, v2.y));
        d1[1] = __builtin_bit_cast(u32, __builtin_amdgcn_cvt_pkrtz(v2.z, v2.w));
        d1[2] = __builtin_bit_cast(u32, __builtin_amdgcn_cvt_pkrtz(v3.x, v3.y));
        d1[3] = __builtin_bit_cast(u32, __builtin_amdgcn_cvt_pkrtz(v3.z, v3.w));
        const int base = r * 128;
        const int sw   = (r & 7) << 4;
        *(u32x4*)(&xls[base + ((2 * c0) ^ sw)])      = d0;
        *(u32x4*)(&xls[base + ((2 * c0 + 16) ^ sw)]) = d1;
    }
    __syncthreads();

    // A fragments: tile m rows [m*16, m*16+16), lane row = m*16+lo, k-chunk hi*8.
    half8 Af[4][2];
#pragma unroll
    for (int m = 0; m < 4; ++m)
#pragma unroll
        for (int ks = 0; ks < 2; ++ks) {
            const int row = m * 16 + lo;
            Af[m][ks] = *(const half8*)(
                &xls[row * 128 + ((ks * 64 + hi * 16) ^ ((row & 7) << 4))]);
        }

    // Compute + store. C/D: col = lo, row = hi*4 + q.
#pragma unroll
    for (int nt = 0; nt < 6; ++nt) {
        const int g    = w * 96 + nt * 16 + lo;
        const int gate = g >> 7;
        const int j    = g & 127;
#pragma unroll
        for (int m = 0; m < 4; ++m) {
            f32x4 acc = {bias[nt], bias[nt], bias[nt], bias[nt]};
            acc = __builtin_amdgcn_mfma_f32_16x16x32_f16(Af[m][0], Bfr[nt][0], acc, 0, 0, 0);
            acc = __builtin_amdgcn_mfma_f32_16x16x32_f16(Af[m][1], Bfr[nt][1], acc, 0, 0, 0);
            const int r0 = rowBase + m * 16 + hi * 4;
#pragma unroll
            for (int q = 0; q < 4; ++q) {
                const f16 val = (f16)acc[q];
                const size_t row = (size_t)(r0 + q);
                if (gate == 0)      xR[row * 128 + j] = val;
                else if (gate == 1) xZN[row * 256 + 2 * j] = val;
                else                xZN[row * 256 + 2 * j + 1] = val;
            }
        }
    }
}

// ---------------- K2: MFMA recurrence + fused out-proj (R18 — best measured:
// 814 us dispatch, 954 cy/step). Gate chains 2+2; direct per-lane b16 h-write;
// strength-reduced stream pointers (2-step strides: xr +256 f16, xzn +512 f16).
__global__ __launch_bounds__(512, 2) void gru_mfma(
    const float* __restrict__ W_hh, const float* __restrict__ b_hh,
    const f16* __restrict__ xR, const f16* __restrict__ xZN,
    const float* __restrict__ W_out, const float* __restrict__ b_out,
    float* __restrict__ latents, float* __restrict__ out)
{
    __shared__ __align__(16) unsigned char hsm[2][1024];  // [b][j] f16, b-parity XOR

    const int tid = threadIdx.x;
    const int w   = tid >> 6;
    const int l   = tid & 63;
    const int lo  = l & 15;
    const int hi  = l >> 4;
    const int jj  = w * 16 + lo;      // this lane's hidden column
    const int bb0 = blockIdx.x * 4;   // 4 batches per block

    // Gate B fragments: lane lo -> col jj, hi -> k-chunk of 8.
    half8 Bf[3][4];
#pragma unroll
    for (int gt = 0; gt < 3; ++gt)
#pragma unroll
        for (int ks = 0; ks < 4; ++ks) {
            const float* wp = W_hh + (size_t)(gt * 128 + jj) * 128 + ks * 32 + hi * 8;
            half8 hv;
#pragma unroll
            for (int q = 0; q < 8; ++q) hv[q] = (f16)wp[q];
            Bf[gt][ks] = hv;
        }
#pragma unroll
    for (int gt = 0; gt < 3; ++gt)
#pragma unroll
        for (int ks = 0; ks < 4; ++ks)
            asm volatile("" : "+v"(Bf[gt][ks]));

    // Out-proj B fragments: all waves hold W_out rows (jj & 63).
    const int oc = jj & 63;
    half8 Bw[4];
#pragma unroll
    for (int ks = 0; ks < 4; ++ks) {
        const float* wp = W_out + (size_t)oc * 128 + ks * 32 + hi * 8;
        half8 hv;
#pragma unroll
        for (int q = 0; q < 8; ++q) hv[q] = (f16)wp[q];
        Bw[ks] = hv;
    }
#pragma unroll
    for (int ks = 0; ks < 4; ++ks) asm volatile("" : "+v"(Bw[ks]));
    const float bo = b_out[oc];

    const float br = b_hh[jj];
    const float bz = b_hh[128 + jj];
    const float bn = b_hh[256 + jj];

    // Strength-reduced per-lane streams for (b = bb0 + hi, j = jj).
    const f16* xrpA  = xR  + (size_t)(bb0 + hi) * Tt * 128 + jj;          // t even
    const f16* xrpB  = xrpA + 128;                                        // t odd
    const f16* xznpA = xZN + (size_t)(bb0 + hi) * Tt * 256 + 2 * jj;
    const f16* xznpB = xznpA + 256;
    float*     latp  = latents + (size_t)(bb0 + hi) * Tt * 128 + jj;
    float*     outp  = out     + (size_t)(bb0 + hi) * Tt * 64  + oc;

    // LDS addresses (R9-validated layout; direct per-lane b16 write).
    const int waddr = hi * 256 + ((2 * jj) ^ ((hi & 1) << 6));
    const int rxor  = ((lo >> 2) & 1) << 6;
    const int rb    = (lo << 6);   // = (lo>>2)*256 for lo in {0,4,8,12}

    // 2-deep x prefetch: set A serves even t, set B serves odd t.
    f16 xrA = xrpA[0];
    f16 xrB = xrpB[0];
    u32 xzA = *(const u32*)xznpA;
    u32 xzB = *(const u32*)xznpB;
    xrpA += 256; xrpB += 256;       // advance 2 steps: 2 x 128 f16
    xznpA += 512; xznpB += 512;     // advance 2 steps: 2 x 256 f16

    float hreg = 0.f;
    half8 A[4];
    {
        half8 z8 = {};
#pragma unroll
        for (int ks = 0; ks < 4; ++ks) A[ks] = z8;   // rows != 4b stay zero forever
    }

// Out-proj for row TR (A[ks] = latents[TR] fragments); COND picks wave group.
#define OUTSTEP(TR, COND)                                                        \
    if (COND) {                                                                  \
        f32x4 aco0 = {bo, bo, bo, bo};                                           \
        f32x4 aco1 = {0.f, 0.f, 0.f, 0.f};                                       \
        aco0 = __builtin_amdgcn_mfma_f32_16x16x32_f16(A[0], Bw[0], aco0, 0, 0, 0); \
        aco1 = __builtin_amdgcn_mfma_f32_16x16x32_f16(A[1], Bw[1], aco1, 0, 0, 0); \
        aco0 = __builtin_amdgcn_mfma_f32_16x16x32_f16(A[2], Bw[2], aco0, 0, 0, 0); \
        aco1 = __builtin_amdgcn_mfma_f32_16x16x32_f16(A[3], Bw[3], aco1, 0, 0, 0); \
        outp[(size_t)(TR) * 64] = aco0[0] + aco1[0];                             \
    }

#define GSTEP(T, WP, XRC, XZC, XRP, XZNP, OCOND)                                 \
    {                                                                            \
        const int t_ = (T);                                                      \
        const float xr_ = (float)XRC;                                            \
        const float xz_ = cvt_lo(XZC);                                           \
        const float xn_ = cvt_hi(XZC);                                           \
        if (t_ + 2 < Tt) {                                                       \
            XRC = XRP[0];                                                        \
            XZC = *(const u32*)XZNP;                                             \
            XRP += 256; XZNP += 512;                                             \
        }                                                                        \
        /* gate MFMAs: 2+2 split chains per gate */                              \
        f32x4 accr0 = {br, br, br, br},     accr1 = {0.f, 0.f, 0.f, 0.f};        \
        f32x4 accz0 = {bz, bz, bz, bz},     accz1 = {0.f, 0.f, 0.f, 0.f};        \
        f32x4 accn0 = {bn, bn, bn, bn},     accn1 = {0.f, 0.f, 0.f, 0.f};        \
        accr0 = __builtin_amdgcn_mfma_f32_16x16x32_f16(A[0], Bf[0][0], accr0, 0, 0, 0); \
        accz0 = __builtin_amdgcn_mfma_f32_16x16x32_f16(A[0], Bf[1][0], accz0, 0, 0, 0); \
        accn0 = __builtin_amdgcn_mfma_f32_16x16x32_f16(A[0], Bf[2][0], accn0, 0, 0, 0); \
        accr1 = __builtin_amdgcn_mfma_f32_16x16x32_f16(A[1], Bf[0][1], accr1, 0, 0, 0); \
        accz1 = __builtin_amdgcn_mfma_f32_16x16x32_f16(A[1], Bf[1][1], accz1, 0, 0, 0); \
        accn1 = __builtin_amdgcn_mfma_f32_16x16x32_f16(A[1], Bf[2][1], accn1, 0, 0, 0); \
        accr0 = __builtin_amdgcn_mfma_f32_16x16x32_f16(A[2], Bf[0][2], accr0, 0, 0, 0); \
        accz0 = __builtin_amdgcn_mfma_f32_16x16x32_f16(A[2], Bf[1][2], accz0, 0, 0, 0); \
        accn0 = __builtin_amdgcn_mfma_f32_16x16x32_f16(A[2], Bf[2][2], accn0, 0, 0, 0); \
        accr1 = __builtin_amdgcn_mfma_f32_16x16x32_f16(A[3], Bf[0][3], accr1, 0, 0, 0); \
        accz1 = __builtin_amdgcn_mfma_f32_16x16x32_f16(A[3], Bf[1][3], accz1, 0, 0, 0); \
        accn1 = __builtin_amdgcn_mfma_f32_16x16x32_f16(A[3], Bf[2][3], accn1, 0, 0, 0); \
        /* off-chain while gate chains drain: out-proj of row t-1 */             \
        if (t_ > 0) { OUTSTEP(t_ - 1, OCOND) }                                   \
        /* batch bb0+hi row (=4*hi) lives in reg 0 of this lane group */         \
        const float r = __builtin_amdgcn_rcpf(1.f + __expf(-(accr0[0] + accr1[0] + xr_))); \
        const float z = __builtin_amdgcn_rcpf(1.f + __expf(-(accz0[0] + accz1[0] + xz_))); \
        const float a = xn_ + r * (accn0[0] + accn1[0]);                         \
        const float n = 1.f - 2.f * __builtin_amdgcn_rcpf(__expf(2.f * a) + 1.f); \
        const float hnew = n + z * (hreg - n);                                   \
        hreg = hnew;                                                             \
        latp[(size_t)t_ * 128] = hnew;                                           \
        *(f16*)(&hsm[WP][waddr]) = (f16)hnew;   /* direct b16, layout-identical */ \
        __syncthreads();                                                         \
        if (!(lo & 3)) {                                                         \
            _Pragma("unroll") for (int ks = 0; ks < 4; ++ks)                     \
                A[ks] = *(const half8*)(&hsm[WP][rb + ((ks * 64 + hi * 16) ^ rxor)]); \
        }                                                                        \
    }

    for (int t = 0; t < Tt; t += 2) {
        GSTEP(t,     0, xrA, xzA, xrpA, xznpA, (w >= 4))  // row t-1 odd -> waves 4-7
        GSTEP(t + 1, 1, xrB, xzB, xrpB, xznpB, (w < 4))   // row t even -> waves 0-3
    }

    // Epilogue: row Tt-1 (odd) out-proj from the final A fragments.
    OUTSTEP(Tt - 1, (w >= 4))
#undef GSTEP
#undef OUTSTEP
}

extern "C" void kernel_launch(void* const* d_in, const int* in_sizes, int n_in,
                              void* d_out, int out_size, void* d_ws, size_t ws_size,
                              hipStream_t stream) {
    const float* inputs = (const float*)d_in[0];
    const float* W_ih   = (const float*)d_in[1];
    const float* W_hh   = (const float*)d_in[2];
    const float* b_ih   = (const float*)d_in[3];
    const float* b_hh   = (const float*)d_in[4];
    const float* W_out  = (const float*)d_in[5];
    const float* b_out  = (const float*)d_in[6];

    float* out     = (float*)d_out;
    float* latents = out + (size_t)Bb * Tt * Oo;

    // x_proj staging (f16): r-gates [B][T][128]; z/n interleaved [B][T][128][2].
    const size_t xbytes = (size_t)Bb * Tt * Gg * sizeof(f16);  // 100,663,296 B
    f16 *xR, *xZN;
    if (ws_size >= xbytes) {
        xR  = (f16*)d_ws;
        xZN = xR + (size_t)Bb * Tt * Hh;
    } else {
        // Alias into d_out: xR fits exactly in the output region, xZN exactly
        // in the latents region (rows byte-aligned 1:1). K2's latents store at
        // (b,t) hits xZN row (b,t), last read at step t-2's prefetch; K2's out
        // store at (b,t-1) hits xR row (b,t-1), last read at step t-3. Both
        // strictly read-before-write per lane-column.
        xR  = (f16*)d_out;
        xZN = (f16*)latents;
    }

    xproj_mfma<<<2048, 256, 0, stream>>>(inputs, W_ih, b_ih, xR, xZN);
    gru_mfma<<<16, 512, 0, stream>>>(W_hh, b_hh, xR, xZN, W_out, b_out,
                                     latents, out);
}